// Round 10
// baseline (366.652 us; speedup 1.0000x reference)
//
#include <hip/hip_runtime.h>
#include <hip/hip_bf16.h>

// N=32 time, 32x32 grid, C=64 (H=4 x D=16), 3x3x3 offsets (M=27), 2 layers.
// R10: back to 3 launches (R9 measured software grid barriers at ~50us each —
// net loss). Keeps R9's HW-verified numerics cuts (no-max softmax, bf16-only
// residual) and adds jcol fragment dedup: h-fragment depends only on
// (di, jcol=dj+ci, t), so load 6 fragment-pairs per (di,t) instead of 24.

typedef short short8_t __attribute__((ext_vector_type(8)));
typedef float floatx4 __attribute__((ext_vector_type(4)));

__device__ __forceinline__ short f2bs(float f) {
    __hip_bfloat16 h = __float2bfloat16(f);
    return *reinterpret_cast<short*>(&h);
}
__device__ __forceinline__ float bs2f(short s) {
    union { unsigned u; float f; } v;
    v.u = ((unsigned)(unsigned short)s) << 16;
    return v.f;
}
// swizzled halo addressing: rowid in [0,324), 8 chunks of 8 shorts, pitch 64
__device__ __forceinline__ int hn_idx(int rowid, int chunk) {
    return rowid * 64 + ((chunk ^ (rowid & 7)) << 3);
}

// ---------------- prep: repack weights + BN partial sums ----------------
__global__ void prep_kernel(const float* __restrict__ Wq, const float* __restrict__ Wk,
                            const float* __restrict__ Wv, short* __restrict__ dst,
                            const float* __restrict__ x, float* __restrict__ sums) {
    if (blockIdx.x < 220) {
        int t = blockIdx.x * 256 + threadIdx.x;
        if (t >= 110 * 512) return;
        int mat  = t >> 9;
        int rem  = t & 511;
        int kk   = rem >> 8;
        int nt   = (rem >> 6) & 3;
        int lane = rem & 63;
        int krow = kk * 32 + (lane >> 4) * 8;
        int col  = nt * 16 + (lane & 15);
        const float* W;
        if (mat < 2)       W = Wq + mat * 4096;
        else if (mat < 56) W = Wk + (mat - 2) * 4096;
        else               W = Wv + (mat - 56) * 4096;
        short8_t v;
        #pragma unroll
        for (int j = 0; j < 8; ++j) v[j] = f2bs(W[(krow + j) * 64 + col]);
        *(short8_t*)&dst[(size_t)mat * 4096 + ((kk * 4 + nt) * 64 + lane) * 8] = v;
    } else {
        int bid = blockIdx.x - 220;
        int t = bid * 256 + threadIdx.x;          // 8192 threads x 3 float4
        const float4* x4 = (const float4*)x;
        float4 v0 = x4[t * 3 + 0], v1 = x4[t * 3 + 1], v2 = x4[t * 3 + 2];
        float vv[6];
        vv[0] = v0.x + v0.w + v1.z + v2.y;
        vv[1] = v0.y + v1.x + v1.w + v2.z;
        vv[2] = v0.z + v1.y + v2.x + v2.w;
        vv[3] = v0.x*v0.x + v0.w*v0.w + v1.z*v1.z + v2.y*v2.y;
        vv[4] = v0.y*v0.y + v1.x*v1.x + v1.w*v1.w + v2.z*v2.z;
        vv[5] = v0.z*v0.z + v1.y*v1.y + v2.x*v2.x + v2.w*v2.w;
        #pragma unroll
        for (int i = 0; i < 6; ++i) {
            #pragma unroll
            for (int off = 1; off < 64; off <<= 1) vv[i] += __shfl_xor(vv[i], off);
        }
        __shared__ float part[4][6];
        if ((threadIdx.x & 63) == 0) {
            #pragma unroll
            for (int i = 0; i < 6; ++i) part[threadIdx.x >> 6][i] = vv[i];
        }
        __syncthreads();
        if (threadIdx.x < 6)
            sums[bid * 8 + threadIdx.x] = part[0][threadIdx.x] + part[1][threadIdx.x] +
                                          part[2][threadIdx.x] + part[3][threadIdx.x];
    }
}

// ---------------- fused attention layer ----------------
// grid (b=8, a=32, nb=2); block 512 = 8 waves; wave = g2*4 + head;
// g2=0 -> m in [0,14), g2=1 -> [14,27). Cells bb0..bb0+3.
template <bool FIRST>
__global__ __launch_bounds__(512, 4)
void layer_fused(const float* __restrict__ x, const float* __restrict__ sums,
                 const float* __restrict__ W_in, const float* __restrict__ b_in,
                 const short* __restrict__ hbf_in, short* __restrict__ hbf_out,
                 const float* __restrict__ Wout, const float* __restrict__ bout,
                 float* __restrict__ out,
                 const short* __restrict__ wqB, const float* __restrict__ bq,
                 const short* __restrict__ wkB, const float* __restrict__ bk,
                 const short* __restrict__ wvB, const float* __restrict__ bv) {
    __shared__ short HnS[324 * 64];   // 41.5 KB; reused for state merge + hf
    __shared__ float Waux[256];
    __shared__ float bn6[6];

    const int tid = threadIdx.x;
    const int bb0 = blockIdx.x * 4, a = blockIdx.y, nb = blockIdx.z;

    if (FIRST) {
        if (tid < 3) {
            float s = 0.f, qq = 0.f;
            #pragma unroll
            for (int p = 0; p < 32; ++p) { s += sums[p * 8 + tid]; qq += sums[p * 8 + 3 + tid]; }
            float mean = s * (1.f / 32768.f);
            float var  = qq * (1.f / 32768.f) - mean * mean;
            bn6[tid]     = mean;
            bn6[3 + tid] = rsqrtf(var + 1e-5f);
        }
        if (tid < 192)      Waux[tid] = W_in[tid];
        else if (tid < 256) Waux[tid] = b_in[tid - 192];
    } else {
        if (tid < 192)      Waux[tid] = Wout[tid];
        else if (tid < 195) Waux[tid] = bout[tid - 192];
    }
    __syncthreads();

    float mean0 = 0, mean1 = 0, mean2 = 0, rs0 = 0, rs1 = 0, rs2 = 0;
    if (FIRST) {
        mean0 = bn6[0]; mean1 = bn6[1]; mean2 = bn6[2];
        rs0 = bn6[3]; rs1 = bn6[4]; rs2 = bn6[5];
    }

    // ---- stage halo: 324 rows x 8 chunks of 8 bf16 ----
    for (int id = tid; id < 2592; id += 512) {
        int rowid = id >> 3, cc = id & 7;
        int r = rowid % 18;
        int rw = rowid / 18;           // spa*6 + jcol
        int spa = rw / 6, jcol = rw - spa * 6;
        int aa = a + spa - 1, bb = bb0 + jcol - 1;
        int n  = nb * 16 + r - 1;
        short8_t v = {0, 0, 0, 0, 0, 0, 0, 0};
        if ((unsigned)n < 32u && (unsigned)aa < 32u && (unsigned)bb < 32u) {
            int cell = (n * 32 + aa) * 32 + bb;
            if (FIRST) {
                float xn0 = (x[cell*3+0] - mean0) * rs0;
                float xn1 = (x[cell*3+1] - mean1) * rs1;
                float xn2 = (x[cell*3+2] - mean2) * rs2;
                #pragma unroll
                for (int j = 0; j < 8; ++j) {
                    int c = cc * 8 + j;
                    float h = Waux[192+c] + xn0*Waux[c] + xn1*Waux[64+c] + xn2*Waux[128+c];
                    v[j] = f2bs(h);
                }
            } else {
                v = *(const short8_t*)&hbf_in[cell * 64 + cc * 8];
            }
        }
        *(short8_t*)&HnS[hn_idx(rowid, cc)] = v;
    }
    __syncthreads();

    const int lane = tid & 63;
    const int wv8  = tid >> 6;
    const int w    = wv8 & 3;        // head
    const int g2   = wv8 >> 2;       // m-group
    const int e    = lane & 15;      // column n (local time row)
    const int q    = lane >> 4;      // quad
    const int c0   = w * 16 + q * 4;

    bool va[3], vb[6];
    #pragma unroll
    for (int d = 0; d < 3; ++d) va[d] = (unsigned)(a + d - 1) < 32u;
    #pragma unroll
    for (int j = 0; j < 6; ++j) vb[j] = (unsigned)(bb0 + j - 1) < 32u;

    // ---- Q^T projection per cell (center: di=1, jcol=ci+1) ----
    floatx4 qv[4];
    {
        short8_t wq0 = *(const short8_t*)&wqB[((0 * 4 + w) * 64 + lane) * 8];
        short8_t wq1 = *(const short8_t*)&wqB[((1 * 4 + w) * 64 + lane) * 8];
        const float4 bq4 = *(const float4*)&bq[c0];
        #pragma unroll
        for (int ci = 0; ci < 4; ++ci) {
            const int row = (6 + ci + 1) * 18 + e + 1;
            short8_t h0 = *(const short8_t*)&HnS[hn_idx(row, q)];
            short8_t h1 = *(const short8_t*)&HnS[hn_idx(row, 4 + q)];
            floatx4 acc = {0, 0, 0, 0};
            acc = __builtin_amdgcn_mfma_f32_16x16x32_bf16(wq0, h0, acc, 0, 0, 0);
            acc = __builtin_amdgcn_mfma_f32_16x16x32_bf16(wq1, h1, acc, 0, 0, 0);
            qv[ci][0] = acc[0] + bq4.x; qv[ci][1] = acc[1] + bq4.y;
            qv[ci][2] = acc[2] + bq4.z; qv[ci][3] = acc[3] + bq4.w;
        }
    }

    // ---- fused K/V pass, no-max softmax; jcol fragment dedup ----
    floatx4 o[4] = {{0,0,0,0},{0,0,0,0},{0,0,0,0},{0,0,0,0}};
    float ss[4] = {0.f, 0.f, 0.f, 0.f};

    const int mstart = g2 ? 14 : 0;
    const int mend   = g2 ? 27 : 14;
    for (int di = 0; di < 3; ++di) {
        if (!va[di]) continue;
        for (int t = 0; t < 3; ++t) {
            const int m0 = t * 9 + di * 3;
            if (m0 + 2 < mstart || m0 >= mend) continue;   // no dj in range
            // load the 6 jcol fragment-pairs once (serves all (dj,ci))
            short8_t f0[6], f1[6];
            #pragma unroll
            for (int j = 0; j < 6; ++j) {
                const int row = (di * 6 + j) * 18 + e + t;
                f0[j] = *(const short8_t*)&HnS[hn_idx(row, q)];
                f1[j] = *(const short8_t*)&HnS[hn_idx(row, 4 + q)];
            }
            #pragma unroll
            for (int dj = 0; dj < 3; ++dj) {
                const int m = m0 + dj;
                if (m < mstart || m >= mend) continue;     // wave-uniform
                short8_t wk0 = *(const short8_t*)&wkB[m * 4096 + ((0 * 4 + w) * 64 + lane) * 8];
                short8_t wk1 = *(const short8_t*)&wkB[m * 4096 + ((1 * 4 + w) * 64 + lane) * 8];
                short8_t wv0 = *(const short8_t*)&wvB[m * 4096 + ((0 * 4 + w) * 64 + lane) * 8];
                short8_t wv1 = *(const short8_t*)&wvB[m * 4096 + ((1 * 4 + w) * 64 + lane) * 8];
                const float4 bk4 = *(const float4*)&bk[m * 64 + c0];
                const float4 bv4 = *(const float4*)&bv[m * 64 + c0];
                #pragma unroll
                for (int ci = 0; ci < 4; ++ci) {
                    if (!vb[dj + ci]) continue;
                    short8_t h0 = f0[dj + ci];
                    short8_t h1 = f1[dj + ci];
                    floatx4 kacc = {0, 0, 0, 0};
                    kacc = __builtin_amdgcn_mfma_f32_16x16x32_bf16(wk0, h0, kacc, 0, 0, 0);
                    kacc = __builtin_amdgcn_mfma_f32_16x16x32_bf16(wk1, h1, kacc, 0, 0, 0);
                    floatx4 vacc = {0, 0, 0, 0};
                    vacc = __builtin_amdgcn_mfma_f32_16x16x32_bf16(wv0, h0, vacc, 0, 0, 0);
                    vacc = __builtin_amdgcn_mfma_f32_16x16x32_bf16(wv1, h1, vacc, 0, 0, 0);
                    float p = (kacc[0] + bk4.x) * qv[ci][0] + (kacc[1] + bk4.y) * qv[ci][1]
                            + (kacc[2] + bk4.z) * qv[ci][2] + (kacc[3] + bk4.w) * qv[ci][3];
                    p += __shfl_xor(p, 16);
                    p += __shfl_xor(p, 32);
                    float wgt = __expf(p);
                    ss[ci] += wgt;
                    o[ci][0] += wgt * (vacc[0] + bv4.x);
                    o[ci][1] += wgt * (vacc[1] + bv4.y);
                    o[ci][2] += wgt * (vacc[2] + bv4.z);
                    o[ci][3] += wgt * (vacc[3] + bv4.w);
                }
            }
        }
    }

    // ---- combine the two m-groups (plain sums) through (dead) halo LDS ----
    __syncthreads();
    float* stbuf = (float*)HnS;            // [head][lane][ci][5] = 5120 floats
    if (g2 == 1) {
        #pragma unroll
        for (int ci = 0; ci < 4; ++ci) {
            float* d = &stbuf[(((w * 64 + lane) * 4) + ci) * 5];
            d[0] = ss[ci];
            d[1] = o[ci][0]; d[2] = o[ci][1]; d[3] = o[ci][2]; d[4] = o[ci][3];
        }
    }
    __syncthreads();
    if (g2 == 0) {
        #pragma unroll
        for (int ci = 0; ci < 4; ++ci) {
            const float* d = &stbuf[(((w * 64 + lane) * 4) + ci) * 5];
            float inv = 1.0f / (ss[ci] + d[0]);
            o[ci][0] = (o[ci][0] + d[1]) * inv;
            o[ci][1] = (o[ci][1] + d[2]) * inv;
            o[ci][2] = (o[ci][2] + d[3]) * inv;
            o[ci][3] = (o[ci][3] + d[4]) * inv;
        }
    }

    // ---- epilogue ----
    const int n = nb * 16 + e;
    if (FIRST) {
        if (g2 == 0) {
            #pragma unroll
            for (int ci = 0; ci < 4; ++ci) {
                int cell = (n * 32 + a) * 32 + bb0 + ci;
                float xn0 = (x[cell*3+0] - mean0) * rs0;
                float xn1 = (x[cell*3+1] - mean1) * rs1;
                float xn2 = (x[cell*3+2] - mean2) * rs2;
                short4 hb; short* hbp = (short*)&hb;
                #pragma unroll
                for (int i = 0; i < 4; ++i) {
                    int c = c0 + i;
                    float res = Waux[192+c] + xn0*Waux[c] + xn1*Waux[64+c] + xn2*Waux[128+c];
                    hbp[i] = f2bs(o[ci][i] + res);
                }
                *(short4*)&hbf_out[cell * 64 + c0] = hb;
            }
        }
    } else {
        __syncthreads();                   // stbuf reads done; reuse LDS for hf
        float* hf = (float*)HnS;           // [4 cells][16 rows][pitch 68]
        if (g2 == 0) {
            #pragma unroll
            for (int ci = 0; ci < 4; ++ci) {
                int cell = (n * 32 + a) * 32 + bb0 + ci;
                short4 hb = *(const short4*)&hbf_in[cell * 64 + c0];
                float* d = &hf[(ci * 16 + e) * 68 + c0];
                d[0] = o[ci][0] + bs2f(hb.x);
                d[1] = o[ci][1] + bs2f(hb.y);
                d[2] = o[ci][2] + bs2f(hb.z);
                d[3] = o[ci][3] + bs2f(hb.w);
            }
        }
        __syncthreads();
        if (tid < 192) {
            int rowglob = tid / 3, f = tid - rowglob * 3;   // rowglob = ci*16 + row
            int ci = rowglob >> 4, row = rowglob & 15;
            float acc = Waux[192 + f];
            #pragma unroll 8
            for (int cc = 0; cc < 64; ++cc) acc += hf[rowglob * 68 + cc] * Waux[cc * 3 + f];
            int nn = nb * 16 + row;
            out[((nn * 32 + a) * 32 + bb0 + ci) * 3 + f] = acc;
        }
    }
}

extern "C" void kernel_launch(void* const* d_in, const int* in_sizes, int n_in,
                              void* d_out, int out_size, void* d_ws, size_t ws_size,
                              hipStream_t stream) {
    const float* x     = (const float*)d_in[0];
    const float* W_in  = (const float*)d_in[1];
    const float* b_in  = (const float*)d_in[2];
    const float* W_out = (const float*)d_in[3];
    const float* b_out = (const float*)d_in[4];
    const float* Wq    = (const float*)d_in[5];
    const float* bq    = (const float*)d_in[6];
    const float* Wk    = (const float*)d_in[7];
    const float* bk    = (const float*)d_in[8];
    const float* Wv    = (const float*)d_in[9];
    const float* bv    = (const float*)d_in[10];

    float* ws    = (float*)d_ws;
    float* sums  = ws;                          // 32 x 8 floats (BN partials)
    short* h1bf  = (short*)(ws + 256);          // 2M shorts (4 MB)
    short* wB    = h1bf + 2097152;              // 110 x 4096 bf16 (0.9 MB)
    float* out   = (float*)d_out;

    prep_kernel<<<252, 256, 0, stream>>>(Wq, Wk, Wv, wB, x, sums);

    const short* wq0 = wB;                const short* wq1 = wB + 4096;
    const short* wk0 = wB + 2 * 4096;     const short* wk1 = wB + (2 + 27) * 4096;
    const short* wv0 = wB + 56 * 4096;    const short* wv1 = wB + (56 + 27) * 4096;

    dim3 grid(8, 32, 2);
    layer_fused<true><<<grid, 512, 0, stream>>>(
        x, sums, W_in, b_in, nullptr, h1bf, nullptr, nullptr, nullptr,
        wq0, bq, wk0, bk, wv0, bv);
    layer_fused<false><<<grid, 512, 0, stream>>>(
        nullptr, nullptr, nullptr, nullptr, h1bf, nullptr, W_out, b_out, out,
        wq1, bq + 64, wk1, bk + 1728, wv1, bv + 1728);
}

// Round 11
// 144.940 us; speedup vs baseline: 2.5297x; 2.5297x over previous
//
#include <hip/hip_runtime.h>
#include <hip/hip_bf16.h>

// N=32 time, 32x32 grid, C=64 (H=4 x D=16), 3x3x3 offsets (M=27), 2 layers.
// R11 = R7 loop structure (per-(m,ci) LDS fragment loads; NO fragment arrays —
// R10's f0[6]/f1[6] dedup spilled to scratch: 600MB HBM traffic, 3x slower)
// + R9-verified cuts: no-max softmax, magic divides, bf16-only residual.

typedef short short8_t __attribute__((ext_vector_type(8)));
typedef float floatx4 __attribute__((ext_vector_type(4)));

__device__ __forceinline__ short f2bs(float f) {
    __hip_bfloat16 h = __float2bfloat16(f);
    return *reinterpret_cast<short*>(&h);
}
__device__ __forceinline__ float bs2f(short s) {
    union { unsigned u; float f; } v;
    v.u = ((unsigned)(unsigned short)s) << 16;
    return v.f;
}
// swizzled halo addressing: rowid in [0,324), 8 chunks of 8 shorts, pitch 64
__device__ __forceinline__ int hn_idx(int rowid, int chunk) {
    return rowid * 64 + ((chunk ^ (rowid & 7)) << 3);
}

// ---------------- prep: repack weights + BN partial sums ----------------
__global__ void prep_kernel(const float* __restrict__ Wq, const float* __restrict__ Wk,
                            const float* __restrict__ Wv, short* __restrict__ dst,
                            const float* __restrict__ x, float* __restrict__ sums) {
    if (blockIdx.x < 220) {
        int t = blockIdx.x * 256 + threadIdx.x;
        if (t >= 110 * 512) return;
        int mat  = t >> 9;
        int rem  = t & 511;
        int kk   = rem >> 8;
        int nt   = (rem >> 6) & 3;
        int lane = rem & 63;
        int krow = kk * 32 + (lane >> 4) * 8;
        int col  = nt * 16 + (lane & 15);
        const float* W;
        if (mat < 2)       W = Wq + mat * 4096;
        else if (mat < 56) W = Wk + (mat - 2) * 4096;
        else               W = Wv + (mat - 56) * 4096;
        short8_t v;
        #pragma unroll
        for (int j = 0; j < 8; ++j) v[j] = f2bs(W[(krow + j) * 64 + col]);
        *(short8_t*)&dst[(size_t)mat * 4096 + ((kk * 4 + nt) * 64 + lane) * 8] = v;
    } else {
        int bid = blockIdx.x - 220;
        int t = bid * 256 + threadIdx.x;          // 8192 threads x 3 float4
        const float4* x4 = (const float4*)x;
        float4 v0 = x4[t * 3 + 0], v1 = x4[t * 3 + 1], v2 = x4[t * 3 + 2];
        float vv[6];
        vv[0] = v0.x + v0.w + v1.z + v2.y;
        vv[1] = v0.y + v1.x + v1.w + v2.z;
        vv[2] = v0.z + v1.y + v2.x + v2.w;
        vv[3] = v0.x*v0.x + v0.w*v0.w + v1.z*v1.z + v2.y*v2.y;
        vv[4] = v0.y*v0.y + v1.x*v1.x + v1.w*v1.w + v2.z*v2.z;
        vv[5] = v0.z*v0.z + v1.y*v1.y + v2.x*v2.x + v2.w*v2.w;
        #pragma unroll
        for (int i = 0; i < 6; ++i) {
            #pragma unroll
            for (int off = 1; off < 64; off <<= 1) vv[i] += __shfl_xor(vv[i], off);
        }
        __shared__ float part[4][6];
        if ((threadIdx.x & 63) == 0) {
            #pragma unroll
            for (int i = 0; i < 6; ++i) part[threadIdx.x >> 6][i] = vv[i];
        }
        __syncthreads();
        if (threadIdx.x < 6)
            sums[bid * 8 + threadIdx.x] = part[0][threadIdx.x] + part[1][threadIdx.x] +
                                          part[2][threadIdx.x] + part[3][threadIdx.x];
    }
}

// ---------------- fused attention layer ----------------
// grid (b=8, a=32, nb=2); block 512 = 8 waves; wave = g2*4 + head;
// g2=0 -> m in [0,14), g2=1 -> [14,27). Cells bb0..bb0+3.
template <bool FIRST>
__global__ __launch_bounds__(512, 4)
void layer_fused(const float* __restrict__ x, const float* __restrict__ sums,
                 const float* __restrict__ W_in, const float* __restrict__ b_in,
                 const short* __restrict__ hbf_in, short* __restrict__ hbf_out,
                 const float* __restrict__ Wout, const float* __restrict__ bout,
                 float* __restrict__ out,
                 const short* __restrict__ wqB, const float* __restrict__ bq,
                 const short* __restrict__ wkB, const float* __restrict__ bk,
                 const short* __restrict__ wvB, const float* __restrict__ bv) {
    __shared__ short HnS[324 * 64];   // 41.5 KB; reused for state merge + hf
    __shared__ float Waux[256];
    __shared__ float bn6[6];

    const int tid = threadIdx.x;
    const int bb0 = blockIdx.x * 4, a = blockIdx.y, nb = blockIdx.z;

    if (FIRST) {
        if (tid < 3) {
            float s = 0.f, qq = 0.f;
            #pragma unroll
            for (int p = 0; p < 32; ++p) { s += sums[p * 8 + tid]; qq += sums[p * 8 + 3 + tid]; }
            float mean = s * (1.f / 32768.f);
            float var  = qq * (1.f / 32768.f) - mean * mean;
            bn6[tid]     = mean;
            bn6[3 + tid] = rsqrtf(var + 1e-5f);
        }
        if (tid < 192)      Waux[tid] = W_in[tid];
        else if (tid < 256) Waux[tid] = b_in[tid - 192];
    } else {
        if (tid < 192)      Waux[tid] = Wout[tid];
        else if (tid < 195) Waux[tid] = bout[tid - 192];
    }
    __syncthreads();

    float mean0 = 0, mean1 = 0, mean2 = 0, rs0 = 0, rs1 = 0, rs2 = 0;
    if (FIRST) {
        mean0 = bn6[0]; mean1 = bn6[1]; mean2 = bn6[2];
        rs0 = bn6[3]; rs1 = bn6[4]; rs2 = bn6[5];
    }

    // ---- stage halo: 324 rows x 8 chunks of 8 bf16 ----
    for (int id = tid; id < 2592; id += 512) {
        int rowid = id >> 3, cc = id & 7;
        int r = rowid % 18;
        int rw = rowid / 18;           // spa*6 + jcol
        int spa = rw / 6, jcol = rw - spa * 6;
        int aa = a + spa - 1, bb = bb0 + jcol - 1;
        int n  = nb * 16 + r - 1;
        short8_t v = {0, 0, 0, 0, 0, 0, 0, 0};
        if ((unsigned)n < 32u && (unsigned)aa < 32u && (unsigned)bb < 32u) {
            int cell = (n * 32 + aa) * 32 + bb;
            if (FIRST) {
                float xn0 = (x[cell*3+0] - mean0) * rs0;
                float xn1 = (x[cell*3+1] - mean1) * rs1;
                float xn2 = (x[cell*3+2] - mean2) * rs2;
                #pragma unroll
                for (int j = 0; j < 8; ++j) {
                    int c = cc * 8 + j;
                    float h = Waux[192+c] + xn0*Waux[c] + xn1*Waux[64+c] + xn2*Waux[128+c];
                    v[j] = f2bs(h);
                }
            } else {
                v = *(const short8_t*)&hbf_in[cell * 64 + cc * 8];
            }
        }
        *(short8_t*)&HnS[hn_idx(rowid, cc)] = v;
    }
    __syncthreads();

    const int lane = tid & 63;
    const int wv8  = tid >> 6;
    const int w    = wv8 & 3;        // head
    const int g2   = wv8 >> 2;       // m-group
    const int e    = lane & 15;      // column n (local time row)
    const int q    = lane >> 4;      // quad
    const int c0   = w * 16 + q * 4;

    bool va[3], vb[6];
    #pragma unroll
    for (int d = 0; d < 3; ++d) va[d] = (unsigned)(a + d - 1) < 32u;
    #pragma unroll
    for (int j = 0; j < 6; ++j) vb[j] = (unsigned)(bb0 + j - 1) < 32u;

    // ---- Q^T projection per cell (center: spa=1, jcol=ci+1) ----
    floatx4 qv[4];
    {
        short8_t wq0 = *(const short8_t*)&wqB[((0 * 4 + w) * 64 + lane) * 8];
        short8_t wq1 = *(const short8_t*)&wqB[((1 * 4 + w) * 64 + lane) * 8];
        const float4 bq4 = *(const float4*)&bq[c0];
        #pragma unroll
        for (int ci = 0; ci < 4; ++ci) {
            const int row = (6 + ci + 1) * 18 + e + 1;
            short8_t h0 = *(const short8_t*)&HnS[hn_idx(row, q)];
            short8_t h1 = *(const short8_t*)&HnS[hn_idx(row, 4 + q)];
            floatx4 acc = {0, 0, 0, 0};
            acc = __builtin_amdgcn_mfma_f32_16x16x32_bf16(wq0, h0, acc, 0, 0, 0);
            acc = __builtin_amdgcn_mfma_f32_16x16x32_bf16(wq1, h1, acc, 0, 0, 0);
            qv[ci][0] = acc[0] + bq4.x; qv[ci][1] = acc[1] + bq4.y;
            qv[ci][2] = acc[2] + bq4.z; qv[ci][3] = acc[3] + bq4.w;
        }
    }

    // ---- fused K/V pass, no-max softmax (rolled m-loop, per-(m,ci) LDS loads) ----
    floatx4 o[4] = {{0,0,0,0},{0,0,0,0},{0,0,0,0},{0,0,0,0}};
    float ss[4] = {0.f, 0.f, 0.f, 0.f};

    const int mstart = g2 ? 14 : 0;
    const int mend   = g2 ? 27 : 14;
    for (int m = mstart; m < mend; ++m) {
        const int t  = (m * 57) >> 9;          // m/9 for m<27
        const int sp = m - 9 * t;
        const int di = (sp * 11) >> 5;         // sp/3 for sp<9
        const int dj = sp - 3 * di;
        if (!va[di]) continue;
        short8_t wk0 = *(const short8_t*)&wkB[m * 4096 + ((0 * 4 + w) * 64 + lane) * 8];
        short8_t wk1 = *(const short8_t*)&wkB[m * 4096 + ((1 * 4 + w) * 64 + lane) * 8];
        short8_t wv0 = *(const short8_t*)&wvB[m * 4096 + ((0 * 4 + w) * 64 + lane) * 8];
        short8_t wv1 = *(const short8_t*)&wvB[m * 4096 + ((1 * 4 + w) * 64 + lane) * 8];
        const float4 bk4 = *(const float4*)&bk[m * 64 + c0];
        const float4 bv4 = *(const float4*)&bv[m * 64 + c0];
        const int rowb = (di * 6 + dj) * 18 + e + t;   // + ci*18
        #pragma unroll
        for (int ci = 0; ci < 4; ++ci) {
            if (!vb[dj + ci]) continue;
            const int row = rowb + ci * 18;
            short8_t h0 = *(const short8_t*)&HnS[hn_idx(row, q)];
            short8_t h1 = *(const short8_t*)&HnS[hn_idx(row, 4 + q)];
            floatx4 kacc = {0, 0, 0, 0};
            kacc = __builtin_amdgcn_mfma_f32_16x16x32_bf16(wk0, h0, kacc, 0, 0, 0);
            kacc = __builtin_amdgcn_mfma_f32_16x16x32_bf16(wk1, h1, kacc, 0, 0, 0);
            floatx4 vacc = {0, 0, 0, 0};
            vacc = __builtin_amdgcn_mfma_f32_16x16x32_bf16(wv0, h0, vacc, 0, 0, 0);
            vacc = __builtin_amdgcn_mfma_f32_16x16x32_bf16(wv1, h1, vacc, 0, 0, 0);
            float p = (kacc[0] + bk4.x) * qv[ci][0] + (kacc[1] + bk4.y) * qv[ci][1]
                    + (kacc[2] + bk4.z) * qv[ci][2] + (kacc[3] + bk4.w) * qv[ci][3];
            p += __shfl_xor(p, 16);
            p += __shfl_xor(p, 32);
            float wgt = __expf(p);
            ss[ci] += wgt;
            o[ci][0] += wgt * (vacc[0] + bv4.x);
            o[ci][1] += wgt * (vacc[1] + bv4.y);
            o[ci][2] += wgt * (vacc[2] + bv4.z);
            o[ci][3] += wgt * (vacc[3] + bv4.w);
        }
    }

    // ---- combine the two m-groups (plain sums) through (dead) halo LDS ----
    __syncthreads();
    float* stbuf = (float*)HnS;            // [head][lane][ci][5] = 5120 floats
    if (g2 == 1) {
        #pragma unroll
        for (int ci = 0; ci < 4; ++ci) {
            float* d = &stbuf[(((w * 64 + lane) * 4) + ci) * 5];
            d[0] = ss[ci];
            d[1] = o[ci][0]; d[2] = o[ci][1]; d[3] = o[ci][2]; d[4] = o[ci][3];
        }
    }
    __syncthreads();
    if (g2 == 0) {
        #pragma unroll
        for (int ci = 0; ci < 4; ++ci) {
            const float* d = &stbuf[(((w * 64 + lane) * 4) + ci) * 5];
            float inv = 1.0f / (ss[ci] + d[0]);
            o[ci][0] = (o[ci][0] + d[1]) * inv;
            o[ci][1] = (o[ci][1] + d[2]) * inv;
            o[ci][2] = (o[ci][2] + d[3]) * inv;
            o[ci][3] = (o[ci][3] + d[4]) * inv;
        }
    }

    // ---- epilogue ----
    const int n = nb * 16 + e;
    if (FIRST) {
        if (g2 == 0) {
            #pragma unroll
            for (int ci = 0; ci < 4; ++ci) {
                int cell = (n * 32 + a) * 32 + bb0 + ci;
                float xn0 = (x[cell*3+0] - mean0) * rs0;
                float xn1 = (x[cell*3+1] - mean1) * rs1;
                float xn2 = (x[cell*3+2] - mean2) * rs2;
                short4 hb; short* hbp = (short*)&hb;
                #pragma unroll
                for (int i = 0; i < 4; ++i) {
                    int c = c0 + i;
                    float res = Waux[192+c] + xn0*Waux[c] + xn1*Waux[64+c] + xn2*Waux[128+c];
                    hbp[i] = f2bs(o[ci][i] + res);
                }
                *(short4*)&hbf_out[cell * 64 + c0] = hb;
            }
        }
    } else {
        __syncthreads();                   // stbuf reads done; reuse LDS for hf
        float* hf = (float*)HnS;           // [4 cells][16 rows][pitch 68]
        if (g2 == 0) {
            #pragma unroll
            for (int ci = 0; ci < 4; ++ci) {
                int cell = (n * 32 + a) * 32 + bb0 + ci;
                short4 hb = *(const short4*)&hbf_in[cell * 64 + c0];
                float* d = &hf[(ci * 16 + e) * 68 + c0];
                d[0] = o[ci][0] + bs2f(hb.x);
                d[1] = o[ci][1] + bs2f(hb.y);
                d[2] = o[ci][2] + bs2f(hb.z);
                d[3] = o[ci][3] + bs2f(hb.w);
            }
        }
        __syncthreads();
        if (tid < 192) {
            int rowglob = tid / 3, f = tid - rowglob * 3;   // rowglob = ci*16 + row
            int ci = rowglob >> 4, row = rowglob & 15;
            float acc = Waux[192 + f];
            #pragma unroll 8
            for (int cc = 0; cc < 64; ++cc) acc += hf[rowglob * 68 + cc] * Waux[cc * 3 + f];
            int nn = nb * 16 + row;
            out[((nn * 32 + a) * 32 + bb0 + ci) * 3 + f] = acc;
        }
    }
}

extern "C" void kernel_launch(void* const* d_in, const int* in_sizes, int n_in,
                              void* d_out, int out_size, void* d_ws, size_t ws_size,
                              hipStream_t stream) {
    const float* x     = (const float*)d_in[0];
    const float* W_in  = (const float*)d_in[1];
    const float* b_in  = (const float*)d_in[2];
    const float* W_out = (const float*)d_in[3];
    const float* b_out = (const float*)d_in[4];
    const float* Wq    = (const float*)d_in[5];
    const float* bq    = (const float*)d_in[6];
    const float* Wk    = (const float*)d_in[7];
    const float* bk    = (const float*)d_in[8];
    const float* Wv    = (const float*)d_in[9];
    const float* bv    = (const float*)d_in[10];

    float* ws    = (float*)d_ws;
    float* sums  = ws;                          // 32 x 8 floats (BN partials)
    short* h1bf  = (short*)(ws + 256);          // 2M shorts (4 MB)
    short* wB    = h1bf + 2097152;              // 110 x 4096 bf16 (0.9 MB)
    float* out   = (float*)d_out;

    prep_kernel<<<252, 256, 0, stream>>>(Wq, Wk, Wv, wB, x, sums);

    const short* wq0 = wB;                const short* wq1 = wB + 4096;
    const short* wk0 = wB + 2 * 4096;     const short* wk1 = wB + (2 + 27) * 4096;
    const short* wv0 = wB + 56 * 4096;    const short* wv1 = wB + (56 + 27) * 4096;

    dim3 grid(8, 32, 2);
    layer_fused<true><<<grid, 512, 0, stream>>>(
        x, sums, W_in, b_in, nullptr, h1bf, nullptr, nullptr, nullptr,
        wq0, bq, wk0, bk, wv0, bv);
    layer_fused<false><<<grid, 512, 0, stream>>>(
        nullptr, nullptr, nullptr, nullptr, h1bf, nullptr, W_out, b_out, out,
        wq1, bq + 64, wk1, bk + 1728, wv1, bv + 1728);
}